// Round 1
// baseline (249.614 us; speedup 1.0000x reference)
//
#include <hip/hip_runtime.h>
#include <hip/hip_bf16.h>

typedef unsigned short u16;
typedef u16 u16x4 __attribute__((ext_vector_type(4)));
typedef u16 u16x8 __attribute__((ext_vector_type(8)));
typedef __bf16 bf16x8 __attribute__((ext_vector_type(8)));
typedef float f32x4 __attribute__((ext_vector_type(4)));

__device__ __forceinline__ u16 f2bf(float f) {
  unsigned u = __float_as_uint(f);
  u += 0x7FFFu + ((u >> 16) & 1u);   // round-to-nearest-even
  return (u16)(u >> 16);
}
__device__ __forceinline__ float bf2f(u16 h) {
  return __uint_as_float(((unsigned)h) << 16);
}
__device__ __forceinline__ float tanh_fast(float x) {
  float t = __expf(2.0f * x);          // +inf -> 1, 0 -> -1, smooth in between
  return 1.0f - 2.0f / (t + 1.0f);
}
__device__ __forceinline__ float sigmoid_fast(float x) {
  return 1.0f / (1.0f + __expf(-x));
}

__device__ __forceinline__ void async16(const void* g, void* lds) {
  __builtin_amdgcn_global_load_lds(
      (const __attribute__((address_space(1))) unsigned int*)g,
      (__attribute__((address_space(3))) unsigned int*)lds,
      16, 0, 0);
}

// ---------------- fp32 -> bf16 convert (4 elems/thread) ----------------
__global__ void cvt_bf16_kernel(const float* __restrict__ src, u16* __restrict__ dst, int n) {
  int i = (blockIdx.x * blockDim.x + threadIdx.x) * 4;
  if (i < n) {
    float4 v = *(const float4*)(src + i);
    u16x4 o = { f2bf(v.x), f2bf(v.y), f2bf(v.z), f2bf(v.w) };
    *(u16x4*)(dst + i) = o;
  }
}

// ---------------- attn weight diff prep: Wd[o][e] = W[o][e][1]-W[o][e][0] ----------------
__global__ void wdprep_kernel(const float* __restrict__ aW, const float* __restrict__ ab,
                              u16* __restrict__ Wd, float* __restrict__ bd) {
  int i = blockIdx.x * blockDim.x + threadIdx.x;   // i in [0, 1024*512)
  int o = i >> 9, e = i & 511;
  float d = aW[(size_t)o * 1024 + e * 2 + 1] - aW[(size_t)o * 1024 + e * 2];
  Wd[i] = f2bf(d);
  if (i < 1024) bd[i] = ab[2 * i + 1] - ab[2 * i];
}

// ---------------- m97-style bf16 GEMM, C = A[M,K] * Bt[N,K]^T, fused epilogue ----------------
// EP==0: outb = bf16(tanh(x + bias[col]))
// EP==1: att = sigmoid(x + bias[col]); outf = att; sa = bf16(obs * att)
template <int EP>
__global__ __launch_bounds__(256)
void gemm_bt(const u16* __restrict__ A, const u16* __restrict__ Bt,
             int M, int N, int K,
             const float* __restrict__ bias,
             u16* __restrict__ outb,
             float* __restrict__ outf,
             const float* __restrict__ obs,
             u16* __restrict__ sa) {
  __shared__ __align__(16) u16 As[128 * 32];
  __shared__ __align__(16) u16 Bs[128 * 32];

  const int tid = threadIdx.x;
  const int lane = tid & 63;
  const int wave = tid >> 6;
  const int bm = blockIdx.x;
  const int bn = blockIdx.y;

  // staging: thread t covers 16B chunk t (rows 0..63) and t+256 (rows 64..127)
  const u16* gA = A + (size_t)(bm * 128 + (tid >> 2)) * K + (tid & 3) * 8;
  const u16* gB = Bt + (size_t)(bn * 128 + (tid >> 2)) * K + (tid & 3) * 8;
  const size_t rowStep = (size_t)64 * K;

  u16* ldsA0 = As + wave * 512;          // wave-uniform bases (lane*16B implicit)
  u16* ldsA1 = As + 2048 + wave * 512;
  u16* ldsB0 = Bs + wave * 512;
  u16* ldsB1 = Bs + 2048 + wave * 512;

  const int wm = (wave >> 1) * 64;
  const int wn = (wave & 1) * 64;
  const int fr = lane & 15;
  const int koff = (lane >> 4) * 8;

  f32x4 acc[4][4];
#pragma unroll
  for (int i = 0; i < 4; ++i)
#pragma unroll
    for (int j = 0; j < 4; ++j)
      acc[i][j] = (f32x4){0.f, 0.f, 0.f, 0.f};

  for (int k0 = 0; k0 < K; k0 += 32) {
    __syncthreads();                 // previous iter done reading LDS
    async16(gA, ldsA0);
    async16(gA + rowStep, ldsA1);
    async16(gB, ldsB0);
    async16(gB + rowStep, ldsB1);
    gA += 32;
    gB += 32;
    __syncthreads();                 // loads drained (vmcnt(0) before barrier)

    bf16x8 a[4], b[4];
#pragma unroll
    for (int i = 0; i < 4; ++i)
      a[i] = *(const bf16x8*)(As + (wm + i * 16 + fr) * 32 + koff);
#pragma unroll
    for (int j = 0; j < 4; ++j)
      b[j] = *(const bf16x8*)(Bs + (wn + j * 16 + fr) * 32 + koff);
#pragma unroll
    for (int i = 0; i < 4; ++i)
#pragma unroll
      for (int j = 0; j < 4; ++j)
        acc[i][j] = __builtin_amdgcn_mfma_f32_16x16x32_bf16(a[i], b[j], acc[i][j], 0, 0, 0);
  }

  // epilogue: D row = wm + i*16 + (lane>>4)*4 + r, col = wn + j*16 + (lane&15)
#pragma unroll
  for (int j = 0; j < 4; ++j) {
    const int col = bn * 128 + wn + j * 16 + fr;
    const float bv = bias[col];
#pragma unroll
    for (int i = 0; i < 4; ++i) {
#pragma unroll
      for (int r = 0; r < 4; ++r) {
        const int row = bm * 128 + wm + i * 16 + (lane >> 4) * 4 + r;
        const float x = acc[i][j][r] + bv;
        const size_t idx = (size_t)row * N + col;
        if (EP == 0) {
          outb[idx] = f2bf(tanh_fast(x));
        } else {
          const float att = sigmoid_fast(x);
          outf[idx] = att;
          sa[idx] = f2bf(obs[idx] * att);
        }
      }
    }
  }
}

// ---------------- v = h2[4096,2048] . W3[2048] + b3 : one wave per row ----------------
__global__ __launch_bounds__(256)
void gemv_v(const u16* __restrict__ h2, const float* __restrict__ W3,
            const float* __restrict__ b3, float* __restrict__ out) {
  int g = blockIdx.x * 256 + threadIdx.x;
  int row = g >> 6;
  int lane = g & 63;
  const u16* rp = h2 + (size_t)row * 2048;
  float sum = 0.f;
#pragma unroll
  for (int p = 0; p < 4; ++p) {
    int base = p * 512 + lane * 8;
    u16x8 hv = *(const u16x8*)(rp + base);
    float4 w0 = *(const float4*)(W3 + base);
    float4 w1 = *(const float4*)(W3 + base + 4);
    sum += bf2f(hv[0]) * w0.x + bf2f(hv[1]) * w0.y + bf2f(hv[2]) * w0.z + bf2f(hv[3]) * w0.w;
    sum += bf2f(hv[4]) * w1.x + bf2f(hv[5]) * w1.y + bf2f(hv[6]) * w1.z + bf2f(hv[7]) * w1.w;
  }
#pragma unroll
  for (int off = 32; off > 0; off >>= 1) sum += __shfl_down(sum, off);
  if (lane == 0) out[row] = sum + b3[0];
}

extern "C" void kernel_launch(void* const* d_in, const int* in_sizes, int n_in,
                              void* d_out, int out_size, void* d_ws, size_t ws_size,
                              hipStream_t stream) {
  const float* obs   = (const float*)d_in[0];   // [4096,1024]
  const float* We    = (const float*)d_in[1];   // [512,1024]
  const float* be    = (const float*)d_in[2];   // [512]
  const float* attnW = (const float*)d_in[3];   // [1024,512,2]
  const float* attnb = (const float*)d_in[4];   // [1024,2]
  const float* W1    = (const float*)d_in[5];   // [2048,1024]
  const float* b1    = (const float*)d_in[6];   // [2048]
  const float* W2    = (const float*)d_in[7];   // [2048,2048]
  const float* b2    = (const float*)d_in[8];   // [2048]
  const float* W3    = (const float*)d_in[9];   // [1,2048]
  const float* b3    = (const float*)d_in[10];  // [1]
  float* out = (float*)d_out;                   // [4096] v, then [4096*1024] attention

  char* ws = (char*)d_ws;
  u16*   We_b  = (u16*)(ws + 0x00000000);   // 1 MB
  u16*   Wd_b  = (u16*)(ws + 0x00100000);   // 1 MB
  u16*   W1_b  = (u16*)(ws + 0x00200000);   // 4 MB
  u16*   W2_b  = (u16*)(ws + 0x00600000);   // 8 MB
  float* bd    = (float*)(ws + 0x00E00000); // 4 KB
  u16*   obs_b = (u16*)(ws + 0x00E01000);   // 8 MB
  u16*   e_b   = (u16*)(ws + 0x01601000);   // 4 MB
  u16*   sa_b  = (u16*)(ws + 0x01A01000);   // 8 MB
  u16*   h1_b  = (u16*)(ws + 0x02201000);   // 16 MB
  u16*   h2_b  = (u16*)(ws + 0x03201000);   // 16 MB (end ≈ 66 MB)

  // input casts to bf16
  cvt_bf16_kernel<<<4096, 256, 0, stream>>>(obs, obs_b, 4096 * 1024);
  cvt_bf16_kernel<<<512, 256, 0, stream>>>(We, We_b, 512 * 1024);
  cvt_bf16_kernel<<<2048, 256, 0, stream>>>(W1, W1_b, 2048 * 1024);
  cvt_bf16_kernel<<<4096, 256, 0, stream>>>(W2, W2_b, 2048 * 2048);
  wdprep_kernel<<<2048, 256, 0, stream>>>(attnW, attnb, Wd_b, bd);

  // e = tanh(obs @ We^T + be)            [4096,512]
  gemm_bt<0><<<dim3(32, 4), 256, 0, stream>>>(obs_b, We_b, 4096, 512, 1024, be, e_b, nullptr, nullptr, nullptr);
  // att = sigmoid(e @ Wd^T + bd); sa = obs*att   [4096,1024]
  gemm_bt<1><<<dim3(32, 8), 256, 0, stream>>>(e_b, Wd_b, 4096, 1024, 512, bd, nullptr, out + 4096, obs, sa_b);
  // h1 = tanh(sa @ W1^T + b1)            [4096,2048]
  gemm_bt<0><<<dim3(32, 16), 256, 0, stream>>>(sa_b, W1_b, 4096, 2048, 1024, b1, h1_b, nullptr, nullptr, nullptr);
  // h2 = tanh(h1 @ W2^T + b2)            [4096,2048]
  gemm_bt<0><<<dim3(32, 16), 256, 0, stream>>>(h1_b, W2_b, 4096, 2048, 2048, b2, h2_b, nullptr, nullptr, nullptr);
  // v = h2 @ W3^T + b3                   [4096]
  gemv_v<<<1024, 256, 0, stream>>>(h2_b, W3, b3, out);
}

// Round 2
// 221.769 us; speedup vs baseline: 1.1256x; 1.1256x over previous
//
#include <hip/hip_runtime.h>
#include <hip/hip_bf16.h>

typedef unsigned short u16;
typedef u16 u16x4 __attribute__((ext_vector_type(4)));
typedef u16 u16x8 __attribute__((ext_vector_type(8)));
typedef __bf16 bf16x8 __attribute__((ext_vector_type(8)));
typedef float f32x4 __attribute__((ext_vector_type(4)));

__device__ __forceinline__ u16 f2bf(float f) {
  unsigned u = __float_as_uint(f);
  u += 0x7FFFu + ((u >> 16) & 1u);   // round-to-nearest-even
  return (u16)(u >> 16);
}
__device__ __forceinline__ float bf2f(u16 h) {
  return __uint_as_float(((unsigned)h) << 16);
}
__device__ __forceinline__ float tanh_fast(float x) {
  float t = __expf(2.0f * x);
  return 1.0f - 2.0f / (t + 1.0f);
}
__device__ __forceinline__ float sigmoid_fast(float x) {
  return 1.0f / (1.0f + __expf(-x));
}

// ---------------- fused prep: all fp32->bf16 casts + attn weight-diff ----------------
__device__ __forceinline__ void cvt4(const float* __restrict__ s, u16* __restrict__ d, int q) {
  float4 v = ((const float4*)s)[q];
  u16x4 o = { f2bf(v.x), f2bf(v.y), f2bf(v.z), f2bf(v.w) };
  ((u16x4*)d)[q] = o;
}

__global__ __launch_bounds__(256)
void prep_kernel(const float* __restrict__ obs, const float* __restrict__ We,
                 const float* __restrict__ W1, const float* __restrict__ W2,
                 const float* __restrict__ aW, const float* __restrict__ ab,
                 u16* __restrict__ obs_b, u16* __restrict__ We_b,
                 u16* __restrict__ W1_b, u16* __restrict__ W2_b,
                 u16* __restrict__ Wd, float* __restrict__ bd) {
  int q = blockIdx.x * 256 + threadIdx.x;          // quad (4-element) index
  if (q < 1048576) { cvt4(obs, obs_b, q); return; }                 // 4096*1024
  q -= 1048576;
  if (q < 131072) { cvt4(We, We_b, q); return; }                    // 512*1024
  q -= 131072;
  if (q < 524288) { cvt4(W1, W1_b, q); return; }                    // 2048*1024
  q -= 524288;
  if (q < 1048576) { cvt4(W2, W2_b, q); return; }                   // 2048*2048
  q -= 1048576;
  if (q < 131072) {                                                  // Wd: 1024*512
    int i0 = q * 4;
    int o = i0 >> 9, e0 = i0 & 511;
    const float* p = aW + (size_t)o * 1024 + e0 * 2;
    float4 v0 = *(const float4*)p;
    float4 v1 = *(const float4*)(p + 4);
    u16x4 od = { f2bf(v0.y - v0.x), f2bf(v0.w - v0.z),
                 f2bf(v1.y - v1.x), f2bf(v1.w - v1.z) };
    *(u16x4*)(Wd + i0) = od;
    if (q < 256) {                                                   // bd: 1024
      float4 a0 = *(const float4*)(ab + q * 8);
      float4 a1 = *(const float4*)(ab + q * 8 + 4);
      float4 ob = { a0.y - a0.x, a0.w - a0.z, a1.y - a1.x, a1.w - a1.z };
      *(float4*)(bd + q * 4) = ob;
    }
  }
}

// ---------------- bf16 GEMM, C = A[M,K] * Bt[N,K]^T, pipelined VGPR staging ----------------
// Loads for tile k+1 issue right after the LDS-ready barrier and stay in flight
// across the ds_read+MFMA section; the compiler's forced vmcnt(0)-before-barrier
// at the top of the next iter coincides with ds_write needing the registers.
// EP==0: outb = bf16(tanh(x + bias[col]))
// EP==1: att = sigmoid(x + bias[col]); outf = att; sa = bf16(obs * att)
template <int EP>
__global__ __launch_bounds__(256)
void gemm_bt(const u16* __restrict__ A, const u16* __restrict__ Bt,
             int M, int N, int K,
             const float* __restrict__ bias,
             u16* __restrict__ outb,
             float* __restrict__ outf,
             const float* __restrict__ obs,
             u16* __restrict__ sa) {
  __shared__ __align__(16) u16 As[128 * 32];
  __shared__ __align__(16) u16 Bs[128 * 32];

  const int tid = threadIdx.x;
  const int lane = tid & 63;
  const int wave = tid >> 6;
  const int bm = blockIdx.x;
  const int bn = blockIdx.y;

  const int r0 = tid >> 2;            // 0..63
  const int c0 = (tid & 3) * 8;       // element offset within 32-wide K chunk
  const u16* gA = A + (size_t)(bm * 128 + r0) * K + c0;
  const u16* gB = Bt + (size_t)(bn * 128 + r0) * K + c0;
  const size_t rowStep = (size_t)64 * K;

  u16* wA0 = As + r0 * 32 + c0;
  u16* wA1 = As + (r0 + 64) * 32 + c0;
  u16* wB0 = Bs + r0 * 32 + c0;
  u16* wB1 = Bs + (r0 + 64) * 32 + c0;

  const int wm = (wave >> 1) * 64;
  const int wn = (wave & 1) * 64;
  const int fr = lane & 15;
  const int koff = (lane >> 4) * 8;

  // prefetch tile k=0 into registers
  u16x8 pa0 = *(const u16x8*)gA;
  u16x8 pa1 = *(const u16x8*)(gA + rowStep);
  u16x8 pb0 = *(const u16x8*)gB;
  u16x8 pb1 = *(const u16x8*)(gB + rowStep);

  f32x4 acc[4][4];
#pragma unroll
  for (int i = 0; i < 4; ++i)
#pragma unroll
    for (int j = 0; j < 4; ++j)
      acc[i][j] = (f32x4){0.f, 0.f, 0.f, 0.f};

  for (int k0 = 0; k0 < K; k0 += 32) {
    __syncthreads();                 // prev iter's LDS readers done (+vmcnt drain of prefetch)
    *(u16x8*)wA0 = pa0;
    *(u16x8*)wA1 = pa1;
    *(u16x8*)wB0 = pb0;
    *(u16x8*)wB1 = pb1;
    __syncthreads();                 // LDS tile ready

    if (k0 + 32 < K) {               // issue next-tile loads; in flight across MFMA section
      gA += 32; gB += 32;
      pa0 = *(const u16x8*)gA;
      pa1 = *(const u16x8*)(gA + rowStep);
      pb0 = *(const u16x8*)gB;
      pb1 = *(const u16x8*)(gB + rowStep);
    }

    bf16x8 a[4], b[4];
#pragma unroll
    for (int i = 0; i < 4; ++i)
      a[i] = *(const bf16x8*)(As + (wm + i * 16 + fr) * 32 + koff);
#pragma unroll
    for (int j = 0; j < 4; ++j)
      b[j] = *(const bf16x8*)(Bs + (wn + j * 16 + fr) * 32 + koff);
#pragma unroll
    for (int i = 0; i < 4; ++i)
#pragma unroll
      for (int j = 0; j < 4; ++j)
        acc[i][j] = __builtin_amdgcn_mfma_f32_16x16x32_bf16(a[i], b[j], acc[i][j], 0, 0, 0);
  }

  // epilogue: D row = wm + i*16 + (lane>>4)*4 + r, col = wn + j*16 + (lane&15)
#pragma unroll
  for (int j = 0; j < 4; ++j) {
    const int col = bn * 128 + wn + j * 16 + fr;
    const float bv = bias[col];
#pragma unroll
    for (int i = 0; i < 4; ++i) {
#pragma unroll
      for (int r = 0; r < 4; ++r) {
        const int row = bm * 128 + wm + i * 16 + (lane >> 4) * 4 + r;
        const float x = acc[i][j][r] + bv;
        const size_t idx = (size_t)row * N + col;
        if (EP == 0) {
          outb[idx] = f2bf(tanh_fast(x));
        } else {
          const float att = sigmoid_fast(x);
          outf[idx] = att;
          sa[idx] = f2bf(obs[idx] * att);
        }
      }
    }
  }
}

// ---------------- v = h2[4096,2048] . W3[2048] + b3 : one wave per row ----------------
__global__ __launch_bounds__(256)
void gemv_v(const u16* __restrict__ h2, const float* __restrict__ W3,
            const float* __restrict__ b3, float* __restrict__ out) {
  int g = blockIdx.x * 256 + threadIdx.x;
  int row = g >> 6;
  int lane = g & 63;
  const u16* rp = h2 + (size_t)row * 2048;
  float sum = 0.f;
#pragma unroll
  for (int p = 0; p < 4; ++p) {
    int base = p * 512 + lane * 8;
    u16x8 hv = *(const u16x8*)(rp + base);
    float4 w0 = *(const float4*)(W3 + base);
    float4 w1 = *(const float4*)(W3 + base + 4);
    sum += bf2f(hv[0]) * w0.x + bf2f(hv[1]) * w0.y + bf2f(hv[2]) * w0.z + bf2f(hv[3]) * w0.w;
    sum += bf2f(hv[4]) * w1.x + bf2f(hv[5]) * w1.y + bf2f(hv[6]) * w1.z + bf2f(hv[7]) * w1.w;
  }
#pragma unroll
  for (int off = 32; off > 0; off >>= 1) sum += __shfl_down(sum, off);
  if (lane == 0) out[row] = sum + b3[0];
}

extern "C" void kernel_launch(void* const* d_in, const int* in_sizes, int n_in,
                              void* d_out, int out_size, void* d_ws, size_t ws_size,
                              hipStream_t stream) {
  const float* obs   = (const float*)d_in[0];   // [4096,1024]
  const float* We    = (const float*)d_in[1];   // [512,1024]
  const float* be    = (const float*)d_in[2];   // [512]
  const float* attnW = (const float*)d_in[3];   // [1024,512,2]
  const float* attnb = (const float*)d_in[4];   // [1024,2]
  const float* W1    = (const float*)d_in[5];   // [2048,1024]
  const float* b1    = (const float*)d_in[6];   // [2048]
  const float* W2    = (const float*)d_in[7];   // [2048,2048]
  const float* b2    = (const float*)d_in[8];   // [2048]
  const float* W3    = (const float*)d_in[9];   // [1,2048]
  const float* b3    = (const float*)d_in[10];  // [1]
  float* out = (float*)d_out;                   // [4096] v, then [4096*1024] attention

  char* ws = (char*)d_ws;
  u16*   We_b  = (u16*)(ws + 0x00000000);   // 1 MB
  u16*   Wd_b  = (u16*)(ws + 0x00100000);   // 1 MB
  u16*   W1_b  = (u16*)(ws + 0x00200000);   // 4 MB
  u16*   W2_b  = (u16*)(ws + 0x00600000);   // 8 MB
  float* bd    = (float*)(ws + 0x00E00000); // 4 KB
  u16*   obs_b = (u16*)(ws + 0x00E01000);   // 8 MB
  u16*   e_b   = (u16*)(ws + 0x01601000);   // 4 MB
  u16*   sa_b  = (u16*)(ws + 0x01A01000);   // 8 MB
  u16*   h1_b  = (u16*)(ws + 0x02201000);   // 16 MB
  u16*   h2_b  = (u16*)(ws + 0x03201000);   // 16 MB (end ≈ 66 MB)

  // all casts + attn weight prep in ONE launch (2883584 quads)
  prep_kernel<<<11264, 256, 0, stream>>>(obs, We, W1, W2, attnW, attnb,
                                         obs_b, We_b, W1_b, W2_b, Wd_b, bd);

  // e = tanh(obs @ We^T + be)            [4096,512]
  gemm_bt<0><<<dim3(32, 4), 256, 0, stream>>>(obs_b, We_b, 4096, 512, 1024, be, e_b, nullptr, nullptr, nullptr);
  // att = sigmoid(e @ Wd^T + bd); sa = obs*att   [4096,1024]
  gemm_bt<1><<<dim3(32, 8), 256, 0, stream>>>(e_b, Wd_b, 4096, 1024, 512, bd, nullptr, out + 4096, obs, sa_b);
  // h1 = tanh(sa @ W1^T + b1)            [4096,2048]
  gemm_bt<0><<<dim3(32, 16), 256, 0, stream>>>(sa_b, W1_b, 4096, 2048, 1024, b1, h1_b, nullptr, nullptr, nullptr);
  // h2 = tanh(h1 @ W2^T + b2)            [4096,2048]
  gemm_bt<0><<<dim3(32, 16), 256, 0, stream>>>(h1_b, W2_b, 4096, 2048, 2048, b2, h2_b, nullptr, nullptr, nullptr);
  // v = h2 @ W3^T + b3                   [4096]
  gemv_v<<<1024, 256, 0, stream>>>(h2_b, W3, b3, out);
}

// Round 3
// 218.523 us; speedup vs baseline: 1.1423x; 1.0149x over previous
//
#include <hip/hip_runtime.h>
#include <hip/hip_bf16.h>

typedef unsigned short u16;
typedef u16 u16x4 __attribute__((ext_vector_type(4)));
typedef u16 u16x8 __attribute__((ext_vector_type(8)));
typedef __bf16 bf16x8 __attribute__((ext_vector_type(8)));
typedef float f32x4 __attribute__((ext_vector_type(4)));

__device__ __forceinline__ u16 f2bf(float f) {
  unsigned u = __float_as_uint(f);
  u += 0x7FFFu + ((u >> 16) & 1u);   // round-to-nearest-even
  return (u16)(u >> 16);
}
__device__ __forceinline__ float bf2f(u16 h) {
  return __uint_as_float(((unsigned)h) << 16);
}
__device__ __forceinline__ float tanh_fast(float x) {
  float t = __expf(2.0f * x);
  return 1.0f - 2.0f / (t + 1.0f);
}
__device__ __forceinline__ float sigmoid_fast(float x) {
  return 1.0f / (1.0f + __expf(-x));
}

__device__ __forceinline__ void async16(const void* g, void* lds) {
  __builtin_amdgcn_global_load_lds(
      (const __attribute__((address_space(1))) unsigned int*)g,
      (__attribute__((address_space(3))) unsigned int*)lds,
      16, 0, 0);
}

// ---------------- fused prep: all fp32->bf16 casts + attn weight-diff ----------------
__device__ __forceinline__ void cvt4(const float* __restrict__ s, u16* __restrict__ d, int q) {
  float4 v = ((const float4*)s)[q];
  u16x4 o = { f2bf(v.x), f2bf(v.y), f2bf(v.z), f2bf(v.w) };
  ((u16x4*)d)[q] = o;
}

__global__ __launch_bounds__(256)
void prep_kernel(const float* __restrict__ obs, const float* __restrict__ We,
                 const float* __restrict__ W1, const float* __restrict__ W2,
                 const float* __restrict__ aW, const float* __restrict__ ab,
                 u16* __restrict__ obs_b, u16* __restrict__ We_b,
                 u16* __restrict__ W1_b, u16* __restrict__ W2_b,
                 u16* __restrict__ Wd, float* __restrict__ bd) {
  int q = blockIdx.x * 256 + threadIdx.x;          // quad (4-element) index
  if (q < 1048576) { cvt4(obs, obs_b, q); return; }                 // 4096*1024
  q -= 1048576;
  if (q < 131072) { cvt4(We, We_b, q); return; }                    // 512*1024
  q -= 131072;
  if (q < 524288) { cvt4(W1, W1_b, q); return; }                    // 2048*1024
  q -= 524288;
  if (q < 1048576) { cvt4(W2, W2_b, q); return; }                   // 2048*2048
  q -= 1048576;
  if (q < 131072) {                                                  // Wd: 1024*512
    int i0 = q * 4;
    int o = i0 >> 9, e0 = i0 & 511;
    const float* p = aW + (size_t)o * 1024 + e0 * 2;
    float4 v0 = *(const float4*)p;
    float4 v1 = *(const float4*)(p + 4);
    u16x4 od = { f2bf(v0.y - v0.x), f2bf(v0.w - v0.z),
                 f2bf(v1.y - v1.x), f2bf(v1.w - v1.z) };
    *(u16x4*)(Wd + i0) = od;
    if (q < 256) {                                                   // bd: 1024
      float4 a0 = *(const float4*)(ab + q * 8);
      float4 a1 = *(const float4*)(ab + q * 8 + 4);
      float4 ob = { a0.y - a0.x, a0.w - a0.z, a1.y - a1.x, a1.w - a1.z };
      *(float4*)(bd + q * 4) = ob;
    }
  }
}

// ---------------- bf16 GEMM, C = A[M,K] * Bt[N,K]^T ----------------
// glds staging, double-buffered LDS, ONE barrier per K-iter:
//   barrier -> glds tile k+1 into buf[(k+1)&1] -> ds_read buf[k&1] + MFMA
// The forced vmcnt(0)-before-barrier drains loads that had the whole MFMA
// section in flight. No ds_write traffic, no prefetch VGPRs.
// Tiles sized for >=4 blocks/CU occupancy (the m102 lever).
// EP==0: outb = bf16(tanh(x + bias[col]))
// EP==1: att = sigmoid(x + bias[col]); outf = att; sa = bf16(obs * att)
template <int BM, int BN, int EP>
__global__ __launch_bounds__(256)
void gemm_bt(const u16* __restrict__ A, const u16* __restrict__ Bt,
             int M, int N, int K,
             const float* __restrict__ bias,
             u16* __restrict__ outb,
             float* __restrict__ outf,
             const float* __restrict__ obs,
             u16* __restrict__ sa) {
  constexpr int MI = BM / 32;          // MFMA frags per wave (M)
  constexpr int NJ = BN / 32;          // MFMA frags per wave (N)
  constexpr int CA = BM / 16;          // 1KB chunks for A tile
  constexpr int CHUNKS = (BM + BN) / 16;
  constexpr int CPW = CHUNKS / 4;      // chunks per wave

  __shared__ __align__(16) u16 As[2][BM * 32];
  __shared__ __align__(16) u16 Bs[2][BN * 32];

  const int tid = threadIdx.x;
  const int lane = tid & 63;
  const int wave = tid >> 6;
  const int bm = blockIdx.x;
  const int bn = blockIdx.y;

  // staging chunks: chunk c covers 16 rows (64 lanes, 4 lanes/row, 16B/lane)
  const u16* gsrc[CPW];
  u16* ld0[CPW];
  u16* ld1[CPW];
#pragma unroll
  for (int q = 0; q < CPW; ++q) {
    const int c = wave * CPW + q;
    if (c < CA) {
      const int r = c * 16;
      gsrc[q] = A + (size_t)(bm * BM + r + (lane >> 2)) * K + (lane & 3) * 8;
      ld0[q] = &As[0][r * 32];
      ld1[q] = &As[1][r * 32];
    } else {
      const int r = (c - CA) * 16;
      gsrc[q] = Bt + (size_t)(bn * BN + r + (lane >> 2)) * K + (lane & 3) * 8;
      ld0[q] = &Bs[0][r * 32];
      ld1[q] = &Bs[1][r * 32];
    }
  }

  const int wm = (wave >> 1) * (BM / 2);
  const int wn = (wave & 1) * (BN / 2);
  const int fr = lane & 15;
  const int koff = (lane >> 4) * 8;

  const int T = K >> 5;

  // prologue: stage tile 0 -> buf 0
#pragma unroll
  for (int q = 0; q < CPW; ++q) async16(gsrc[q], ld0[q]);
#pragma unroll
  for (int q = 0; q < CPW; ++q) gsrc[q] += 32;

  f32x4 acc[MI][NJ];
#pragma unroll
  for (int i = 0; i < MI; ++i)
#pragma unroll
    for (int j = 0; j < NJ; ++j)
      acc[i][j] = (f32x4){0.f, 0.f, 0.f, 0.f};

  for (int k = 0; k < T; ++k) {
    __syncthreads();                 // buf[k&1] staged (vmcnt drained); prev reads done
    if (k + 1 < T) {                 // stage tile k+1; in flight across MFMA section
      const int nxt = (k + 1) & 1;
#pragma unroll
      for (int q = 0; q < CPW; ++q) async16(gsrc[q], nxt ? ld1[q] : ld0[q]);
#pragma unroll
      for (int q = 0; q < CPW; ++q) gsrc[q] += 32;
    }
    const u16* Ar = &As[k & 1][0];
    const u16* Br = &Bs[k & 1][0];

    bf16x8 a[MI], b[NJ];
#pragma unroll
    for (int i = 0; i < MI; ++i)
      a[i] = *(const bf16x8*)(Ar + (wm + i * 16 + fr) * 32 + koff);
#pragma unroll
    for (int j = 0; j < NJ; ++j)
      b[j] = *(const bf16x8*)(Br + (wn + j * 16 + fr) * 32 + koff);
#pragma unroll
    for (int i = 0; i < MI; ++i)
#pragma unroll
      for (int j = 0; j < NJ; ++j)
        acc[i][j] = __builtin_amdgcn_mfma_f32_16x16x32_bf16(a[i], b[j], acc[i][j], 0, 0, 0);
  }

  // epilogue: D row = wm + i*16 + (lane>>4)*4 + r, col = wn + j*16 + (lane&15)
#pragma unroll
  for (int j = 0; j < NJ; ++j) {
    const int col = bn * BN + wn + j * 16 + fr;
    const float bv = bias[col];
#pragma unroll
    for (int i = 0; i < MI; ++i) {
#pragma unroll
      for (int r = 0; r < 4; ++r) {
        const int row = bm * BM + wm + i * 16 + (lane >> 4) * 4 + r;
        const float x = acc[i][j][r] + bv;
        const size_t idx = (size_t)row * N + col;
        if (EP == 0) {
          outb[idx] = f2bf(tanh_fast(x));
        } else {
          const float att = sigmoid_fast(x);
          outf[idx] = att;
          sa[idx] = f2bf(obs[idx] * att);
        }
      }
    }
  }
}

// ---------------- v = h2[4096,2048] . W3[2048] + b3 : one wave per row ----------------
__global__ __launch_bounds__(256)
void gemv_v(const u16* __restrict__ h2, const float* __restrict__ W3,
            const float* __restrict__ b3, float* __restrict__ out) {
  int g = blockIdx.x * 256 + threadIdx.x;
  int row = g >> 6;
  int lane = g & 63;
  const u16* rp = h2 + (size_t)row * 2048;
  float sum = 0.f;
#pragma unroll
  for (int p = 0; p < 4; ++p) {
    int base = p * 512 + lane * 8;
    u16x8 hv = *(const u16x8*)(rp + base);
    float4 w0 = *(const float4*)(W3 + base);
    float4 w1 = *(const float4*)(W3 + base + 4);
    sum += bf2f(hv[0]) * w0.x + bf2f(hv[1]) * w0.y + bf2f(hv[2]) * w0.z + bf2f(hv[3]) * w0.w;
    sum += bf2f(hv[4]) * w1.x + bf2f(hv[5]) * w1.y + bf2f(hv[6]) * w1.z + bf2f(hv[7]) * w1.w;
  }
#pragma unroll
  for (int off = 32; off > 0; off >>= 1) sum += __shfl_down(sum, off);
  if (lane == 0) out[row] = sum + b3[0];
}

extern "C" void kernel_launch(void* const* d_in, const int* in_sizes, int n_in,
                              void* d_out, int out_size, void* d_ws, size_t ws_size,
                              hipStream_t stream) {
  const float* obs   = (const float*)d_in[0];   // [4096,1024]
  const float* We    = (const float*)d_in[1];   // [512,1024]
  const float* be    = (const float*)d_in[2];   // [512]
  const float* attnW = (const float*)d_in[3];   // [1024,512,2]
  const float* attnb = (const float*)d_in[4];   // [1024,2]
  const float* W1    = (const float*)d_in[5];   // [2048,1024]
  const float* b1    = (const float*)d_in[6];   // [2048]
  const float* W2    = (const float*)d_in[7];   // [2048,2048]
  const float* b2    = (const float*)d_in[8];   // [2048]
  const float* W3    = (const float*)d_in[9];   // [1,2048]
  const float* b3    = (const float*)d_in[10];  // [1]
  float* out = (float*)d_out;                   // [4096] v, then [4096*1024] attention

  char* ws = (char*)d_ws;
  u16*   We_b  = (u16*)(ws + 0x00000000);   // 1 MB
  u16*   Wd_b  = (u16*)(ws + 0x00100000);   // 1 MB
  u16*   W1_b  = (u16*)(ws + 0x00200000);   // 4 MB
  u16*   W2_b  = (u16*)(ws + 0x00600000);   // 8 MB
  float* bd    = (float*)(ws + 0x00E00000); // 4 KB
  u16*   obs_b = (u16*)(ws + 0x00E01000);   // 8 MB
  u16*   e_b   = (u16*)(ws + 0x01601000);   // 4 MB
  u16*   sa_b  = (u16*)(ws + 0x01A01000);   // 8 MB
  u16*   h1_b  = (u16*)(ws + 0x02201000);   // 16 MB
  u16*   h2_b  = (u16*)(ws + 0x03201000);   // 16 MB (end ≈ 66 MB)

  // all casts + attn weight prep in ONE launch (2883584 quads)
  prep_kernel<<<11264, 256, 0, stream>>>(obs, We, W1, W2, attnW, attnb,
                                         obs_b, We_b, W1_b, W2_b, Wd_b, bd);

  // e = tanh(obs @ We^T + be)            [4096,512]   512 blocks, 2/CU
  gemm_bt<64, 64, 0><<<dim3(64, 8), 256, 0, stream>>>(obs_b, We_b, 4096, 512, 1024, be, e_b, nullptr, nullptr, nullptr);
  // att = sigmoid(e @ Wd^T + bd); sa = obs*att   [4096,1024]   1024 blocks, 4/CU
  gemm_bt<64, 64, 1><<<dim3(64, 16), 256, 0, stream>>>(e_b, Wd_b, 4096, 1024, 512, bd, nullptr, out + 4096, obs, sa_b);
  // h1 = tanh(sa @ W1^T + b1)            [4096,2048]  1024 blocks, 4/CU
  gemm_bt<128, 64, 0><<<dim3(32, 32), 256, 0, stream>>>(sa_b, W1_b, 4096, 2048, 1024, b1, h1_b, nullptr, nullptr, nullptr);
  // h2 = tanh(h1 @ W2^T + b2)            [4096,2048]  1024 blocks, 4/CU
  gemm_bt<128, 64, 0><<<dim3(32, 32), 256, 0, stream>>>(h1_b, W2_b, 4096, 2048, 2048, b2, h2_b, nullptr, nullptr, nullptr);
  // v = h2 @ W3^T + b3                   [4096]
  gemv_v<<<1024, 256, 0, stream>>>(h2_b, W3, b3, out);
}